// Round 12
// baseline (126.211 us; speedup 1.0000x reference)
//
#include <hip/hip_runtime.h>
#include <math.h>

// MatchingLayer (BiMPM-style) — MI355X. Round 12: round-10 two-dispatch
// structure (best measured) + leaner 512-thread k_prep + stride-9 Dscr.
// B=32, L=128, H=100, P=20, C=105.

namespace {
constexpr int B = 32;
constexpr int L = 128;
constexpr int H = 100;
constexpr int P = 20;
constexpr int C = 105;
constexpr int TI = 8;            // i-rows per side tile
constexpr int SMEM_BYTES = 50176;
constexpr float EPSF = 1e-8f;
constexpr float MINV = -1e7f;
}

typedef unsigned short u16;
typedef unsigned int u32;
typedef short sh8 __attribute__((ext_vector_type(8)));   // 8 bf16 (4 VGPRs)
typedef float f4 __attribute__((ext_vector_type(4)));

__device__ __forceinline__ u16 f2bf(float f) {           // RNE f32->bf16
    u32 u = __float_as_uint(f);
    u += 0x7FFFu + ((u >> 16) & 1u);
    return (u16)(u >> 16);
}
__device__ __forceinline__ float bf2f(u32 h) {
    return __uint_as_float(h << 16);
}
__device__ __forceinline__ u32 pack2(float a, float b) {
    return (u32)f2bf(a) | ((u32)f2bf(b) << 16);
}

// ---------------------------------------------------------------- k_prep
// grid (L/8, B, 2), block 512. Block = 8 rows. Phase A: masked vector
// (fp32 + bf16 K=128 pad) + v^2 into LDS. Phase B: wave w = row w, 21 norm
// tasks x 3-lane K-split (63/64 lanes active).
__global__ __launch_bounds__(512) void
k_prep(const float* __restrict__ ctx_p, const int* __restrict__ mask_p,
       const float* __restrict__ ctx_h, const int* __restrict__ mask_h,
       const float* __restrict__ w1,
       float* __restrict__ cp, float* __restrict__ ch,
       u16* __restrict__ cpb, u16* __restrict__ chb,
       float* __restrict__ np_, float* __restrict__ nh_,
       float* __restrict__ nwp, float* __restrict__ nwh)
{
    const int bx = blockIdx.x, b = blockIdx.y, side = blockIdx.z, t = threadIdx.x;
    const int i0 = bx * 8;
    const float* ctx = side ? ctx_h : ctx_p;
    const int*  mask = side ? mask_h : mask_p;
    float* dst  = side ? ch  : cp;
    u16*   dstb = side ? chb : cpb;
    float* nrm  = side ? nh_ : np_;
    float* nw   = side ? nwh : nwp;

    __shared__ __align__(16) float sv2[8][112];

    // phase A: 8 rows x 128 cols = 1024 elems, 2 per thread
    #pragma unroll
    for (int it = 0; it < 2; ++it) {
        int idx = it * 512 + t;
        int rr = idx >> 7, k = idx & 127;
        const int row = b * L + i0 + rr;
        const float m = (float)mask[row];
        float v = 0.f;
        if (k < H) {
            v = ctx[(size_t)row * H + k] * m;
            dst[(size_t)row * H + k] = v;
            sv2[rr][k] = v * v;
        }
        dstb[(size_t)row * 128 + k] = f2bf(v);
    }
    __syncthreads();

    // phase B: wave w -> row w. lane ln<63: g=ln/3 (0..20), seg=ln%3.
    const int wv = t >> 6, ln = t & 63;
    if (ln < 63) {
        const int g = ln / 3, seg = ln - 3 * g;
        const int k0 = (seg == 0) ? 0 : (seg == 1) ? 8 : 16;
        const int k1 = (seg == 0) ? 8 : (seg == 1) ? 16 : 25;
        const float4* v4 = (const float4*)sv2[wv];
        float acc = 0.f;
        if (g < P) {
            const float4* w4 = (const float4*)(w1 + g * H);
            for (int k = k0; k < k1; ++k) {
                float4 w = w4[k], s = v4[k];
                acc += w.x * w.x * s.x + w.y * w.y * s.y +
                       w.z * w.z * s.z + w.w * w.w * s.w;
            }
        } else {
            for (int k = k0; k < k1; ++k) {
                float4 s = v4[k];
                acc += s.x + s.y + s.z + s.w;
            }
        }
        float a1 = __shfl(acc, ln + 1), a2 = __shfl(acc, ln + 2);
        if (seg == 0) {
            const int row = b * L + i0 + wv;
            float s = sqrtf(acc + a1 + a2);
            if (g < P) nw[(size_t)row * P + g] = s;
            else       nrm[row] = s;
        }
    }
}

// ---------------------------------------------------------------- k_main
// 512 threads. bx<P: pair GEMM for p=bx. bx>=P: side tile. (= round 10,
// with Dscr stride 9 to break the scatter-write bank aliasing.)
__global__ __launch_bounds__(512) void
k_main(const float* __restrict__ cp, const float* __restrict__ ch,
       const u16* __restrict__ cpb, const u16* __restrict__ chb,
       const float* __restrict__ np_, const float* __restrict__ nh_,
       const float* __restrict__ nw1p, const float* __restrict__ nw1h,
       const int* __restrict__ mask_p, const int* __restrict__ mask_h,
       const float* __restrict__ w0, const float* __restrict__ w1,
       const float* __restrict__ w2, const float* __restrict__ w3,
       float* __restrict__ out)
{
    __shared__ __align__(16) char smem[SMEM_BYTES];
    const int bx = blockIdx.x, b = blockIdx.y, t = threadIdx.x;
    const int wv = t >> 6, ln = t & 63;
    float* out_p = out;
    float* out_h = out + (size_t)B * L * C;

    if (bx < P) {
        // ==================== pair path ====================
        const int p = bx;
        u16*  sB    = (u16*)smem;                      // [128][136]
        float* snwA = (float*)(smem + 34816);
        float* snwB = (float*)(smem + 35328);
        float* smA  = (float*)(smem + 35840);
        float* smB  = (float*)(smem + 36352);
        float* pJmax= (float*)(smem + 36864);
        float* pJsum= (float*)(smem + 37376);
        float* pImax= (float*)(smem + 37888);          // [8][128]
        float* pIsum= (float*)(smem + 41984);          // [8][128]
        float* sRed = (float*)(smem + 46080);          // 4

        if (t < 128) {
            snwA[t] = nw1p[(b * L + t) * P + p];
            snwB[t] = nw1h[(b * L + t) * P + p];
            smA[t] = (float)mask_p[b * L + t];
            smB[t] = (float)mask_h[b * L + t];
        }
        __syncthreads();

        if (t < 64) {
            float a0 = smB[t], a1 = smB[t + 64];
            float mx = fmaxf(a0, a1), sm = a0 + a1;
            for (int d = 1; d < 64; d <<= 1) {
                mx = fmaxf(mx, __shfl_xor(mx, d));
                sm += __shfl_xor(sm, d);
            }
            if (t == 0) { sRed[2] = mx; sRed[3] = sm; }
        } else if (t < 128) {
            const int l = t - 64;
            float a0 = smA[l], a1 = smA[l + 64];
            float mx = fmaxf(a0, a1), sm = a0 + a1;
            for (int d = 1; d < 64; d <<= 1) {
                mx = fmaxf(mx, __shfl_xor(mx, d));
                sm += __shfl_xor(sm, d);
            }
            if (l == 0) { sRed[0] = mx; sRed[1] = sm; }
        }

        {   // stage B (h-side bf16 rows), padded stride 136
            const uint4* src = (const uint4*)(chb + (size_t)b * L * 128);
            #pragma unroll
            for (int it = 0; it < 4; ++it) {
                int idx = it * 512 + t;
                int row = idx >> 4, kc = (idx & 15) * 8;
                uint4 v = src[idx];
                *(uint4*)&sB[row * 136 + kc] = v;
            }
        }
        __syncthreads();

        const int m = ln & 15, q = ln >> 4;

        float swv[4][8];
        #pragma unroll
        for (int ks = 0; ks < 4; ++ks)
            #pragma unroll
            for (int e = 0; e < 8; ++e) {
                int k = ks * 32 + q * 8 + e;
                float w = (k < H) ? w1[p * H + k] : 0.f;
                swv[ks][e] = w * w;
            }

        f4 acc[8];
        #pragma unroll
        for (int ct = 0; ct < 8; ++ct) acc[ct] = (f4){0.f, 0.f, 0.f, 0.f};

        const uint4* gA = (const uint4*)(cpb + (size_t)(b * L + wv * 16 + m) * 128);

        #pragma unroll
        for (int ks = 0; ks < 4; ++ks) {
            uint4 va = gA[ks * 4 + q];
            sh8 af;
            {
                u32 vs[4] = {va.x, va.y, va.z, va.w};
                u32 r[4];
                #pragma unroll
                for (int e = 0; e < 4; ++e) {
                    float f0 = bf2f(vs[e] & 0xffffu) * swv[ks][2 * e];
                    float f1 = bf2f(vs[e] >> 16) * swv[ks][2 * e + 1];
                    r[e] = (u32)f2bf(f0) | ((u32)f2bf(f1) << 16);
                }
                uint4 o = {r[0], r[1], r[2], r[3]};
                af = __builtin_bit_cast(sh8, o);
            }
            const int ko = ks * 32 + q * 8;
            #pragma unroll
            for (int ct = 0; ct < 8; ++ct) {
                sh8 bb = *(const sh8*)&sB[(ct * 16 + m) * 136 + ko];
                acc[ct] = __builtin_amdgcn_mfma_f32_16x16x32_bf16(af, bb, acc[ct], 0, 0, 0);
            }
        }

        float nB[8], mBv[8], imax[8], isum[8];
        #pragma unroll
        for (int ct = 0; ct < 8; ++ct) {
            const int j = ct * 16 + m;
            nB[ct] = snwB[j]; mBv[ct] = smB[j];
            imax[ct] = MINV; isum[ct] = 0.f;
        }
        #pragma unroll
        for (int reg = 0; reg < 4; ++reg) {
            const int i = wv * 16 + q * 4 + reg;
            const float na = snwA[i];
            const float ma = smA[i];
            float jmax = MINV, jsum = 0.f;
            #pragma unroll
            for (int ct = 0; ct < 8; ++ct) {
                float v = acc[ct][reg] *
                          __builtin_amdgcn_rcpf(fmaxf(na * nB[ct], EPSF));
                jmax = fmaxf(jmax, mBv[ct] > 0.f ? v : MINV);
                jsum += mBv[ct] > 0.f ? v : 0.f;
                imax[ct] = fmaxf(imax[ct], ma > 0.f ? v : MINV);
                isum[ct] += ma > 0.f ? v : 0.f;
            }
            for (int d = 1; d < 16; d <<= 1) {
                jmax = fmaxf(jmax, __shfl_xor(jmax, d));
                jsum += __shfl_xor(jsum, d);
            }
            if (m == 0) { pJmax[i] = jmax; pJsum[i] = jsum; }
        }
        #pragma unroll
        for (int ct = 0; ct < 8; ++ct) {
            float mx = imax[ct], sm = isum[ct];
            mx = fmaxf(mx, __shfl_xor(mx, 16)); sm += __shfl_xor(sm, 16);
            mx = fmaxf(mx, __shfl_xor(mx, 32)); sm += __shfl_xor(sm, 32);
            if (q == 0) { const int j = ct * 16 + m; pImax[wv * 128 + j] = mx; pIsum[wv * 128 + j] = sm; }
        }
        __syncthreads();

        if (t < 128) {
            const int i = t;
            const float ma = smA[i];
            const float mm = ma * sRed[2];
            const float cnt = ma * sRed[3];
            float* orow = out_p + ((size_t)b * L + i) * C;
            orow[23 + p] = pJmax[i] * mm;
            orow[43 + p] = ma * pJsum[i] / fmaxf(cnt, EPSF);

            const float mb = smB[i];
            float hmax = MINV, hsum = 0.f;
            #pragma unroll
            for (int s = 0; s < 8; ++s) {
                hmax = fmaxf(hmax, pImax[s * 128 + i]);
                hsum += pIsum[s * 128 + i];
            }
            float* hrow = out_h + ((size_t)b * L + i) * C;
            hrow[23 + p] = hmax * mb * sRed[0];
            hrow[43 + p] = mb * hsum / fmaxf(mb * sRed[1], EPSF);
        }
    } else {
        // ==================== side path ====================
        const int e = bx - P;
        const int side = e >> 4, tile = e & 15;
        const int i0 = tile * TI;
        const float* A   = side ? ch : cp;
        const float* Bv  = side ? cp : ch;
        const u16*  Ab16 = side ? chb : cpb;
        const u16*  Bvb  = side ? cpb : chb;
        const float* nA_ = side ? nh_ : np_;
        const float* nB_ = side ? np_ : nh_;
        const int* maskA = side ? mask_h : mask_p;
        const int* maskB = side ? mask_p : mask_h;
        float* outBase = out + ((size_t)side * B * L + (size_t)b * L) * C;

        float* scosC = (float*)(smem + 34816);
        float* sa    = (float*)(smem + 38912);
        float* sam   = (float*)(smem + 42496);
        float* sax   = (float*)(smem + 46080);
        float* sl    = (float*)(smem + 49664);
        float* snB   = (float*)(smem + 42496);
        float* snA   = (float*)(smem + 43008);
        u16*  cidx  = (u16*)(smem + 43040);
        int*   pnv   = (int*)(smem + 50112);

        // ---- phase 0: zero scosC; valid-j list (wave 0); sa staging (2-7)
        scosC[t] = 0.f;
        scosC[t + 512] = 0.f;
        if (wv == 0) {
            int m0 = maskB[b * L + ln], m1 = maskB[b * L + 64 + ln];
            unsigned long long b0 = __ballot(m0 > 0);
            unsigned long long b1 = __ballot(m1 > 0);
            unsigned long long pre = (1ull << ln) - 1ull;
            int n0 = __popcll(b0);
            if (m0 > 0) cidx[__popcll(b0 & pre)] = (u16)ln;
            if (m1 > 0) cidx[n0 + __popcll(b1 & pre)] = (u16)(64 + ln);
            if (ln == 0) *pnv = n0 + __popcll(b1);
        } else if (wv >= 2) {
            for (int x = t - 128; x < TI * 128; x += 384) {
                int il = x >> 7, k = x & 127;
                if (k < H) sa[il * 112 + k] = A[((size_t)b * L + i0 + il) * H + k];
            }
        }
        __syncthreads();
        const int nv = *pnv;
        const int nct = (nv + 15) >> 4;

        // ---- phase 1: compact bf16 Bv rows (stride 272 B, zero tail) + norms + sl
        {
            const uint4* src = (const uint4*)(Bvb + (size_t)b * L * 128);
            for (int c = t; c < nct * 256; c += 512) {
                int jj = c >> 4, cc = c & 15;
                uint4 v;
                if (jj < nv) v = src[(int)cidx[jj] * 16 + cc];
                else { v.x = v.y = v.z = v.w = 0u; }
                *(uint4*)(smem + jj * 272 + cc * 16) = v;
            }
            if (t < 128) snB[t] = (t < nv) ? nB_[b * L + (int)cidx[t]] : 0.f;
            else if (t < 136) snA[t - 128] = nA_[b * L + i0 + (t - 128)];
            if (wv == 1) {
                int last = nv - 1; if (last < 0) last = 0;
                const float* lr = Bv + ((size_t)b * L + last) * H;
                sl[ln] = lr[ln];
                if (ln + 64 < H) sl[ln + 64] = lr[ln + 64];
            }
        }
        __syncthreads();

        // ---- phase cos: wave wv owns col-tile ct=wv (nct <= 8)
        const int m = ln & 15, q = ln >> 4;
        if (wv < nct) {
            const uint4* gA = (const uint4*)(Ab16 + (size_t)(b * L + i0 + (m & 7)) * 128);
            f4 acc0 = (f4){0.f, 0.f, 0.f, 0.f};
            #pragma unroll
            for (int ks = 0; ks < 4; ++ks) {
                uint4 va = gA[ks * 4 + q];
                if (m >= 8) { va.x = va.y = va.z = va.w = 0u; }
                sh8 af = __builtin_bit_cast(sh8, va);
                const int ko2 = (ks * 32 + q * 8) * 2;
                sh8 bb = *(const sh8*)(smem + (wv * 16 + m) * 272 + ko2);
                acc0 = __builtin_amdgcn_mfma_f32_16x16x32_bf16(af, bb, acc0, 0, 0, 0);
            }
            if (q < 2) {
                #pragma unroll
                for (int reg = 0; reg < 4; ++reg) {
                    const int i = q * 4 + reg;
                    const int jj = wv * 16 + m;
                    scosC[i * 128 + jj] = acc0[reg] *
                        __builtin_amdgcn_rcpf(fmaxf(snA[i] * snB[jj], EPSF));
                }
            }
        }
        __syncthreads();

        // ---- phase 2: butterfly scalars + attentive am/ax; wave wv = row wv
        {
            const int il = wv;
            const int gi = i0 + il;
            const float mA = (float)maskA[b * L + gi];
            float c0 = scosC[il * 128 + ln], c1 = scosC[il * 128 + 64 + ln];
            float scj = c0 + c1;
            float mv0 = (ln < nv) ? c0 : MINV;
            float mv1 = (ln + 64 < nv) ? c1 : MINV;
            float cmx = fmaxf(mv0, mv1);
            for (int d = 1; d < 64; d <<= 1) {
                scj += __shfl_xor(scj, d);
                cmx = fmaxf(cmx, __shfl_xor(cmx, d));
            }
            const float mm = (nv > 0) ? mA : 0.f;
            if (ln == 0) {
                float* orow = outBase + (size_t)gi * C;
                orow[0] = cmx * mm;
                orow[1] = mA * scj / fmaxf(mA * (float)nv, EPSF);
            }
            if (ln < 50) {
                float am0 = 0.f, am1 = 0.f, ax0 = MINV, ax1 = MINV;
                const u32* bp = (const u32*)smem + ln;       // row stride 68 dwords
                const float* cr = scosC + il * 128;
                #pragma unroll 4
                for (int jj = 0; jj < nv; ++jj) {
                    u32 pk = bp[jj * 68];
                    float cj = cr[jj];
                    float v0 = cj * __uint_as_float(pk << 16);
                    float v1 = cj * __uint_as_float(pk & 0xffff0000u);
                    am0 += v0; am1 += v1;
                    ax0 = fmaxf(ax0, v0); ax1 = fmaxf(ax1, v1);
                }
                const float rs = __builtin_amdgcn_rcpf(fmaxf(scj, EPSF));
                sam[il * 112 + 2 * ln] = am0 * rs; sam[il * 112 + 2 * ln + 1] = am1 * rs;
                sax[il * 112 + 2 * ln] = ax0 * mm; sax[il * 112 + 2 * ln + 1] = ax1 * mm;
            }
        }
        __syncthreads();

        // ---- phase 3a: Bcols (products, bf16, stride 136u16) + w2sq stack
        for (int idx = t; idx < 8 * 8 * 17; idx += 512) {
            int kc = (idx % 17) * 8;
            int tmp = idx / 17;                  // il*8 + col
            int il = tmp >> 3, col = tmp & 7;
            const float* sa_il  = sa  + il * 112;
            const float* sam_il = sam + il * 112;
            const float* sax_il = sax + il * 112;
            const float* p1 = (col >= 4) ? (col == 4 ? sl : col == 5 ? sam_il : sax_il)
                                         : sa_il;
            const float* p2 = (col == 0 || col == 4) ? sl :
                              (col == 1 || col == 5) ? sam_il :
                              (col == 2 || col == 6) ? sax_il : sa_il;
            u32 ow[4];
            #pragma unroll
            for (int e2 = 0; e2 < 4; ++e2) {
                int k0 = kc + 2 * e2;
                float f0 = (col < 7 && k0 < H)     ? p1[k0] * p2[k0]         : 0.f;
                float f1 = (col < 7 && k0 + 1 < H) ? p1[k0 + 1] * p2[k0 + 1] : 0.f;
                ow[e2] = pack2(f0, f1);
            }
            uint4 o = {ow[0], ow[1], ow[2], ow[3]};
            *(uint4*)(smem + (tmp * 136 + kc) * 2) = o;
        }
        for (int idx = t; idx < 64 * 17; idx += 512) {
            int kc = (idx % 17) * 8;
            int row = idx / 17;
            u32 ow[4];
            #pragma unroll
            for (int e2 = 0; e2 < 4; ++e2) {
                int k0 = kc + 2 * e2;
                float f0 = 0.f, f1 = 0.f;
                if (row < 60) {
                    const float* wr = (row < 20) ? w0 + row * H :
                                      (row < 40) ? w2 + (row - 20) * H :
                                                   w3 + (row - 40) * H;
                    if (k0 < H)     { float w = wr[k0];     f0 = w * w; }
                    if (k0 + 1 < H) { float w = wr[k0 + 1]; f1 = w * w; }
                } else if (row == 60) {
                    f0 = (k0 < H) ? 1.f : 0.f;
                    f1 = (k0 + 1 < H) ? 1.f : 0.f;
                }
                ow[e2] = pack2(f0, f1);
            }
            uint4 o = {ow[0], ow[1], ow[2], ow[3]};
            *(uint4*)(smem + 17408 + (row * 136 + kc) * 2) = o;
        }
        __syncthreads();

        // ---- phase 3b: D[61x7] = w2sq x Bcols^T per il (wave wv -> il=wv)
        f4 d3[4];
        #pragma unroll
        for (int Mt = 0; Mt < 4; ++Mt) d3[Mt] = (f4){0.f, 0.f, 0.f, 0.f};
        {
            const int cn = m & 7;
            #pragma unroll
            for (int ks = 0; ks < 4; ++ks) {
                const int ko2 = (ks * 32 + q * 8) * 2;
                sh8 bb = *(const sh8*)(smem + ((wv * 8 + cn) * 136) * 2 + ko2);
                #pragma unroll
                for (int Mt = 0; Mt < 4; ++Mt) {
                    sh8 aa = *(const sh8*)(smem + 17408 + ((Mt * 16 + m) * 136) * 2 + ko2);
                    d3[Mt] = __builtin_amdgcn_mfma_f32_16x16x32_bf16(aa, bb, d3[Mt], 0, 0, 0);
                }
            }
        }
        __syncthreads();   // all MFMA reads done before Dscr overwrites

        if (m < 8) {       // Dscr stride 9 dwords
            #pragma unroll
            for (int Mt = 0; Mt < 4; ++Mt)
                #pragma unroll
                for (int reg = 0; reg < 4; ++reg)
                    ((float*)smem)[wv * 576 + (Mt * 16 + q * 4 + reg) * 9 + m] = d3[Mt][reg];
        }
        __syncthreads();

        // ---- phase 3c: 504 output channels from Dscr
        for (int task = t; task < TI * 63; task += 512) {
            const int il = task / 63, c = task - il * 63;
            int row, dcol, nbcol, chn;
            if (c < 60) {
                const int grp = c / 20;
                row = c; dcol = grp; nbcol = 4 + grp;
                chn = ((grp == 0) ? 3 : (grp == 1) ? 64 : 85) + (c - grp * 20);
            } else {
                const int cc = c - 60;
                row = 60; dcol = cc; nbcol = 4 + cc;
                chn = (cc == 0) ? 2 : (cc == 1) ? 63 : 84;
            }
            const float* Dr = (const float*)smem + il * 576 + row * 9;
            float d = Dr[dcol], na = Dr[3], nb = Dr[nbcol];
            outBase[(size_t)(i0 + il) * C + chn] =
                d / (fmaxf(sqrtf(na), EPSF) * fmaxf(sqrtf(nb), EPSF));
        }
    }
}

// ---------------------------------------------------------------- launch
extern "C" void kernel_launch(void* const* d_in, const int* in_sizes, int n_in,
                              void* d_out, int out_size, void* d_ws, size_t ws_size,
                              hipStream_t stream)
{
    const float* ctx_p = (const float*)d_in[0];
    const int*   mask_p = (const int*)d_in[1];
    const float* ctx_h = (const float*)d_in[2];
    const int*   mask_h = (const int*)d_in[3];
    const float* w0 = (const float*)d_in[4];
    const float* w1 = (const float*)d_in[5];
    const float* w2 = (const float*)d_in[6];
    const float* w3 = (const float*)d_in[7];
    float* out = (float*)d_out;

    float* ws   = (float*)d_ws;
    float* cp   = ws;                       // B*L*H
    float* ch   = cp   + B * L * H;
    float* np_  = ch   + B * L * H;         // B*L
    float* nh_  = np_  + B * L;
    float* nw1p = nh_  + B * L;             // B*L*P
    float* nw1h = nw1p + B * L * P;
    u16*   cpb  = (u16*)(nw1h + B * L * P); // B*L*128 u16
    u16*   chb  = cpb + B * L * 128;

    k_prep<<<dim3(L / 8, B, 2), dim3(512), 0, stream>>>(
        ctx_p, mask_p, ctx_h, mask_h, w1,
        cp, ch, cpb, chb, np_, nh_, nw1p, nw1h);
    k_main<<<dim3(P + 32, B), dim3(512), 0, stream>>>(
        cp, ch, cpb, chb, np_, nh_, nw1p, nw1h, mask_p, mask_h,
        w0, w1, w2, w3, out);
}

// Round 14
// 123.459 us; speedup vs baseline: 1.0223x; 1.0223x over previous
//
#include <hip/hip_runtime.h>
#include <math.h>

// MatchingLayer (BiMPM-style) — MI355X. Round 14: round-13 LDS diet (stride
// 104 u16) + NaN fix: zero the B fragment for ks==3,q>0 in ALL MFMA loops
// (0 x Inf/NaN = NaN — never multiply against OOB garbage).
// Grid (20+32, B) x 512 thr. B=32, L=128, H=100, P=20, C=105.

namespace {
constexpr int B = 32;
constexpr int L = 128;
constexpr int H = 100;
constexpr int P = 20;
constexpr int C = 105;
constexpr int TI = 8;            // i-rows per side tile
constexpr int SMEM_BYTES = 40768;
constexpr float EPSF = 1e-8f;
constexpr float MINV = -1e7f;
}

typedef unsigned short u16;
typedef unsigned int u32;
typedef short sh8 __attribute__((ext_vector_type(8)));   // 8 bf16 (4 VGPRs)
typedef float f4 __attribute__((ext_vector_type(4)));

__device__ __forceinline__ u16 f2bf(float f) {           // RNE f32->bf16
    u32 u = __float_as_uint(f);
    u += 0x7FFFu + ((u >> 16) & 1u);
    return (u16)(u >> 16);
}
__device__ __forceinline__ float bf2f(u32 h) {
    return __uint_as_float(h << 16);
}
__device__ __forceinline__ u32 pack2(float a, float b) {
    return (u32)f2bf(a) | ((u32)f2bf(b) << 16);
}
__device__ __forceinline__ sh8 zfrag() {
    return __builtin_bit_cast(sh8, (uint4){0u, 0u, 0u, 0u});
}

// ---------------------------------------------------------------- k_prep
// grid (L/8, B, 2), block 512. Block = 8 rows. Phase A: masked vector
// (fp32 + bf16 K=128 pad) + v^2 into LDS. Phase B: wave w = row w, 21 norm
// tasks x 3-lane K-split.
__global__ __launch_bounds__(512) void
k_prep(const float* __restrict__ ctx_p, const int* __restrict__ mask_p,
       const float* __restrict__ ctx_h, const int* __restrict__ mask_h,
       const float* __restrict__ w1,
       float* __restrict__ cp, float* __restrict__ ch,
       u16* __restrict__ cpb, u16* __restrict__ chb,
       float* __restrict__ np_, float* __restrict__ nh_,
       float* __restrict__ nwp, float* __restrict__ nwh)
{
    const int bx = blockIdx.x, b = blockIdx.y, side = blockIdx.z, t = threadIdx.x;
    const int i0 = bx * 8;
    const float* ctx = side ? ctx_h : ctx_p;
    const int*  mask = side ? mask_h : mask_p;
    float* dst  = side ? ch  : cp;
    u16*   dstb = side ? chb : cpb;
    float* nrm  = side ? nh_ : np_;
    float* nw   = side ? nwh : nwp;

    __shared__ __align__(16) float sv2[8][112];

    #pragma unroll
    for (int it = 0; it < 2; ++it) {
        int idx = it * 512 + t;
        int rr = idx >> 7, k = idx & 127;
        const int row = b * L + i0 + rr;
        const float m = (float)mask[row];
        float v = 0.f;
        if (k < H) {
            v = ctx[(size_t)row * H + k] * m;
            dst[(size_t)row * H + k] = v;
            sv2[rr][k] = v * v;
        }
        dstb[(size_t)row * 128 + k] = f2bf(v);
    }
    __syncthreads();

    const int wv = t >> 6, ln = t & 63;
    if (ln < 63) {
        const int g = ln / 3, seg = ln - 3 * g;
        const int k0 = (seg == 0) ? 0 : (seg == 1) ? 8 : 16;
        const int k1 = (seg == 0) ? 8 : (seg == 1) ? 16 : 25;
        const float4* v4 = (const float4*)sv2[wv];
        float acc = 0.f;
        if (g < P) {
            const float4* w4 = (const float4*)(w1 + g * H);
            for (int k = k0; k < k1; ++k) {
                float4 w = w4[k], s = v4[k];
                acc += w.x * w.x * s.x + w.y * w.y * s.y +
                       w.z * w.z * s.z + w.w * w.w * s.w;
            }
        } else {
            for (int k = k0; k < k1; ++k) {
                float4 s = v4[k];
                acc += s.x + s.y + s.z + s.w;
            }
        }
        float a1 = __shfl(acc, ln + 1), a2 = __shfl(acc, ln + 2);
        if (seg == 0) {
            const int row = b * L + i0 + wv;
            float s = sqrtf(acc + a1 + a2);
            if (g < P) nw[(size_t)row * P + g] = s;
            else       nrm[row] = s;
        }
    }
}

// ---------------------------------------------------------------- k_main
// 512 threads. bx<P: pair GEMM for p=bx. bx>=P: side tile.
// LDS B-tiles use stride 104 u16 (208 B). For ks==3 && q>0 (k>=104) the
// B fragment is explicitly zeroed — A is zero there too, but OOB garbage
// could be Inf/NaN and 0*Inf=NaN, so the operand must never be garbage.
__global__ __launch_bounds__(512) void
k_main(const float* __restrict__ cp, const float* __restrict__ ch,
       const u16* __restrict__ cpb, const u16* __restrict__ chb,
       const float* __restrict__ np_, const float* __restrict__ nh_,
       const float* __restrict__ nw1p, const float* __restrict__ nw1h,
       const int* __restrict__ mask_p, const int* __restrict__ mask_h,
       const float* __restrict__ w0, const float* __restrict__ w1,
       const float* __restrict__ w2, const float* __restrict__ w3,
       float* __restrict__ out)
{
    __shared__ __align__(16) char smem[SMEM_BYTES];
    const int bx = blockIdx.x, b = blockIdx.y, t = threadIdx.x;
    const int wv = t >> 6, ln = t & 63;
    float* out_p = out;
    float* out_h = out + (size_t)B * L * C;

    if (bx < P) {
        // ==================== pair path ====================
        const int p = bx;
        u16*  sB    = (u16*)smem;                      // [128][104]
        float* snwA = (float*)(smem + 26624);
        float* snwB = (float*)(smem + 27136);
        float* smA  = (float*)(smem + 27648);
        float* smB  = (float*)(smem + 28160);
        float* pJmax= (float*)(smem + 28672);
        float* pJsum= (float*)(smem + 29184);
        float* pImax= (float*)(smem + 29696);          // [8][128]
        float* pIsum= (float*)(smem + 33792);          // [8][128]
        float* sRed = (float*)(smem + 37888);          // 4

        if (t < 128) {
            snwA[t] = nw1p[(b * L + t) * P + p];
            snwB[t] = nw1h[(b * L + t) * P + p];
            smA[t] = (float)mask_p[b * L + t];
            smB[t] = (float)mask_h[b * L + t];
        }
        __syncthreads();

        if (t < 64) {
            float a0 = smB[t], a1 = smB[t + 64];
            float mx = fmaxf(a0, a1), sm = a0 + a1;
            for (int d = 1; d < 64; d <<= 1) {
                mx = fmaxf(mx, __shfl_xor(mx, d));
                sm += __shfl_xor(sm, d);
            }
            if (t == 0) { sRed[2] = mx; sRed[3] = sm; }
        } else if (t < 128) {
            const int l = t - 64;
            float a0 = smA[l], a1 = smA[l + 64];
            float mx = fmaxf(a0, a1), sm = a0 + a1;
            for (int d = 1; d < 64; d <<= 1) {
                mx = fmaxf(mx, __shfl_xor(mx, d));
                sm += __shfl_xor(sm, d);
            }
            if (l == 0) { sRed[0] = mx; sRed[1] = sm; }
        }

        {   // stage B (h-side bf16 rows), stride 104 u16: 128 rows x 13 uint4
            const uint4* src = (const uint4*)(chb + (size_t)b * L * 128);
            for (int idx = t; idx < 128 * 13; idx += 512) {
                int row = idx / 13, cc = idx - row * 13;
                uint4 v = src[row * 16 + cc];
                *(uint4*)&sB[row * 104 + cc * 8] = v;
            }
        }
        __syncthreads();

        const int m = ln & 15, q = ln >> 4;

        float swv[4][8];
        #pragma unroll
        for (int ks = 0; ks < 4; ++ks)
            #pragma unroll
            for (int e = 0; e < 8; ++e) {
                int k = ks * 32 + q * 8 + e;
                float w = (k < H) ? w1[p * H + k] : 0.f;
                swv[ks][e] = w * w;
            }

        f4 acc[8];
        #pragma unroll
        for (int ct = 0; ct < 8; ++ct) acc[ct] = (f4){0.f, 0.f, 0.f, 0.f};

        const uint4* gA = (const uint4*)(cpb + (size_t)(b * L + wv * 16 + m) * 128);

        #pragma unroll
        for (int ks = 0; ks < 4; ++ks) {
            uint4 va = gA[ks * 4 + q];
            sh8 af;
            {
                u32 vs[4] = {va.x, va.y, va.z, va.w};
                u32 r[4];
                #pragma unroll
                for (int e = 0; e < 4; ++e) {
                    float f0 = bf2f(vs[e] & 0xffffu) * swv[ks][2 * e];
                    float f1 = bf2f(vs[e] >> 16) * swv[ks][2 * e + 1];
                    r[e] = (u32)f2bf(f0) | ((u32)f2bf(f1) << 16);
                }
                uint4 o = {r[0], r[1], r[2], r[3]};
                af = __builtin_bit_cast(sh8, o);
            }
            const int ko = ks * 32 + q * 8;
            const bool oob = (ks == 3) && (q > 0);     // k>=104: af==0; bb would be garbage
            #pragma unroll
            for (int ct = 0; ct < 8; ++ct) {
                sh8 bb = oob ? zfrag() : *(const sh8*)&sB[(ct * 16 + m) * 104 + ko];
                acc[ct] = __builtin_amdgcn_mfma_f32_16x16x32_bf16(af, bb, acc[ct], 0, 0, 0);
            }
        }

        float nB[8], mBv[8], imax[8], isum[8];
        #pragma unroll
        for (int ct = 0; ct < 8; ++ct) {
            const int j = ct * 16 + m;
            nB[ct] = snwB[j]; mBv[ct] = smB[j];
            imax[ct] = MINV; isum[ct] = 0.f;
        }
        #pragma unroll
        for (int reg = 0; reg < 4; ++reg) {
            const int i = wv * 16 + q * 4 + reg;
            const float na = snwA[i];
            const float ma = smA[i];
            float jmax = MINV, jsum = 0.f;
            #pragma unroll
            for (int ct = 0; ct < 8; ++ct) {
                float v = acc[ct][reg] *
                          __builtin_amdgcn_rcpf(fmaxf(na * nB[ct], EPSF));
                jmax = fmaxf(jmax, mBv[ct] > 0.f ? v : MINV);
                jsum += mBv[ct] > 0.f ? v : 0.f;
                imax[ct] = fmaxf(imax[ct], ma > 0.f ? v : MINV);
                isum[ct] += ma > 0.f ? v : 0.f;
            }
            for (int d = 1; d < 16; d <<= 1) {
                jmax = fmaxf(jmax, __shfl_xor(jmax, d));
                jsum += __shfl_xor(jsum, d);
            }
            if (m == 0) { pJmax[i] = jmax; pJsum[i] = jsum; }
        }
        #pragma unroll
        for (int ct = 0; ct < 8; ++ct) {
            float mx = imax[ct], sm = isum[ct];
            mx = fmaxf(mx, __shfl_xor(mx, 16)); sm += __shfl_xor(sm, 16);
            mx = fmaxf(mx, __shfl_xor(mx, 32)); sm += __shfl_xor(sm, 32);
            if (q == 0) { const int j = ct * 16 + m; pImax[wv * 128 + j] = mx; pIsum[wv * 128 + j] = sm; }
        }
        __syncthreads();

        if (t < 128) {
            const int i = t;
            const float ma = smA[i];
            const float mm = ma * sRed[2];
            const float cnt = ma * sRed[3];
            float* orow = out_p + ((size_t)b * L + i) * C;
            orow[23 + p] = pJmax[i] * mm;
            orow[43 + p] = ma * pJsum[i] / fmaxf(cnt, EPSF);

            const float mb = smB[i];
            float hmax = MINV, hsum = 0.f;
            #pragma unroll
            for (int s = 0; s < 8; ++s) {
                hmax = fmaxf(hmax, pImax[s * 128 + i]);
                hsum += pIsum[s * 128 + i];
            }
            float* hrow = out_h + ((size_t)b * L + i) * C;
            hrow[23 + p] = hmax * mb * sRed[0];
            hrow[43 + p] = mb * hsum / fmaxf(mb * sRed[1], EPSF);
        }
    } else {
        // ==================== side path ====================
        // BvC [<=128][208B] @0; overlay 3a: Bcols [64][208B] @0 +
        // w2sq [64][208B] @13312; overlay post-3b: Dscr [8][64][9]f32 @0.
        // scosC f[8][128] @26624; sa f[8][100] @30720; sam @33920
        // (pre-phase2 overlay: snB@33920[128]f, snA@34432[8]f,
        // cidx@34464[128]u16); sax @37120; sl f[100] @40320; pnv @40720.
        const int e = bx - P;
        const int side = e >> 4, tile = e & 15;
        const int i0 = tile * TI;
        const float* Bv  = side ? cp : ch;
        const float* A   = side ? ch : cp;
        const u16*  Ab16 = side ? chb : cpb;
        const u16*  Bvb  = side ? cpb : chb;
        const float* nA_ = side ? nh_ : np_;
        const float* nB_ = side ? np_ : nh_;
        const int* maskA = side ? mask_h : mask_p;
        const int* maskB = side ? mask_p : mask_h;
        float* outBase = out + ((size_t)side * B * L + (size_t)b * L) * C;

        float* scosC = (float*)(smem + 26624);
        float* sa    = (float*)(smem + 30720);
        float* sam   = (float*)(smem + 33920);
        float* sax   = (float*)(smem + 37120);
        float* sl    = (float*)(smem + 40320);
        float* snB   = (float*)(smem + 33920);
        float* snA   = (float*)(smem + 34432);
        u16*  cidx  = (u16*)(smem + 34464);
        int*   pnv   = (int*)(smem + 40720);

        // ---- phase 0: zero scosC; valid-j list (wave 0); sa staging (2-7)
        scosC[t] = 0.f;
        scosC[t + 512] = 0.f;
        if (wv == 0) {
            int m0 = maskB[b * L + ln], m1 = maskB[b * L + 64 + ln];
            unsigned long long b0 = __ballot(m0 > 0);
            unsigned long long b1 = __ballot(m1 > 0);
            unsigned long long pre = (1ull << ln) - 1ull;
            int n0 = __popcll(b0);
            if (m0 > 0) cidx[__popcll(b0 & pre)] = (u16)ln;
            if (m1 > 0) cidx[n0 + __popcll(b1 & pre)] = (u16)(64 + ln);
            if (ln == 0) *pnv = n0 + __popcll(b1);
        } else if (wv >= 2) {
            for (int x = t - 128; x < TI * 128; x += 384) {
                int il = x >> 7, k = x & 127;
                if (k < H) sa[il * 100 + k] = A[((size_t)b * L + i0 + il) * H + k];
            }
        }
        __syncthreads();
        const int nv = *pnv;
        const int nct = (nv + 15) >> 4;

        // ---- phase 1: compact bf16 Bv rows (stride 208 B, zero tail) +
        //      norms + sl
        {
            const uint4* src = (const uint4*)(Bvb + (size_t)b * L * 128);
            for (int c = t; c < nct * 208; c += 512) {   // rows x 13 uint4
                int jj = c / 13, cc = c - jj * 13;
                uint4 v;
                if (jj < nv) v = src[(int)cidx[jj] * 16 + cc];
                else { v.x = v.y = v.z = v.w = 0u; }
                *(uint4*)(smem + jj * 208 + cc * 16) = v;
            }
            if (t < 128) snB[t] = (t < nv) ? nB_[b * L + (int)cidx[t]] : 0.f;
            else if (t < 136) snA[t - 128] = nA_[b * L + i0 + (t - 128)];
            if (wv == 1) {
                int last = nv - 1; if (last < 0) last = 0;
                const float* lr = Bv + ((size_t)b * L + last) * H;
                sl[ln] = lr[ln];
                if (ln + 64 < H) sl[ln + 64] = lr[ln + 64];
            }
        }
        __syncthreads();

        // ---- phase cos: wave wv owns col-tile ct=wv (nct <= 8)
        const int m = ln & 15, q = ln >> 4;
        if (wv < nct) {
            const uint4* gA = (const uint4*)(Ab16 + (size_t)(b * L + i0 + (m & 7)) * 128);
            f4 acc0 = (f4){0.f, 0.f, 0.f, 0.f};
            #pragma unroll
            for (int ks = 0; ks < 4; ++ks) {
                uint4 va = gA[ks * 4 + q];
                if (m >= 8) { va.x = va.y = va.z = va.w = 0u; }
                sh8 af = __builtin_bit_cast(sh8, va);   // zero for k>=100
                const int ko2 = (ks * 32 + q * 8) * 2;
                const bool oob = (ks == 3) && (q > 0);
                sh8 bb = oob ? zfrag()
                             : *(const sh8*)(smem + (wv * 16 + m) * 208 + ko2);
                acc0 = __builtin_amdgcn_mfma_f32_16x16x32_bf16(af, bb, acc0, 0, 0, 0);
            }
            if (q < 2) {
                #pragma unroll
                for (int reg = 0; reg < 4; ++reg) {
                    const int i = q * 4 + reg;
                    const int jj = wv * 16 + m;
                    scosC[i * 128 + jj] = acc0[reg] *
                        __builtin_amdgcn_rcpf(fmaxf(snA[i] * snB[jj], EPSF));
                }
            }
        }
        __syncthreads();

        // ---- phase 2: butterfly scalars + attentive am/ax; wave wv = row wv
        {
            const int il = wv;
            const int gi = i0 + il;
            const float mA = (float)maskA[b * L + gi];
            float c0 = scosC[il * 128 + ln], c1 = scosC[il * 128 + 64 + ln];
            float scj = c0 + c1;
            float mv0 = (ln < nv) ? c0 : MINV;
            float mv1 = (ln + 64 < nv) ? c1 : MINV;
            float cmx = fmaxf(mv0, mv1);
            for (int d = 1; d < 64; d <<= 1) {
                scj += __shfl_xor(scj, d);
                cmx = fmaxf(cmx, __shfl_xor(cmx, d));
            }
            const float mm = (nv > 0) ? mA : 0.f;
            if (ln == 0) {
                float* orow = outBase + (size_t)gi * C;
                orow[0] = cmx * mm;
                orow[1] = mA * scj / fmaxf(mA * (float)nv, EPSF);
            }
            if (ln < 50) {
                float am0 = 0.f, am1 = 0.f, ax0 = MINV, ax1 = MINV;
                const u32* bp = (const u32*)smem + ln;   // row stride 52 dwords
                const float* cr = scosC + il * 128;
                #pragma unroll 4
                for (int jj = 0; jj < nv; ++jj) {
                    u32 pk = bp[jj * 52];
                    float cj = cr[jj];
                    float v0 = cj * __uint_as_float(pk << 16);
                    float v1 = cj * __uint_as_float(pk & 0xffff0000u);
                    am0 += v0; am1 += v1;
                    ax0 = fmaxf(ax0, v0); ax1 = fmaxf(ax1, v1);
                }
                const float rs = __builtin_amdgcn_rcpf(fmaxf(scj, EPSF));
                sam[il * 100 + 2 * ln] = am0 * rs; sam[il * 100 + 2 * ln + 1] = am1 * rs;
                sax[il * 100 + 2 * ln] = ax0 * mm; sax[il * 100 + 2 * ln + 1] = ax1 * mm;
            }
        }
        __syncthreads();

        // ---- phase 3a: Bcols (products, bf16, stride 104u16 @0) + w2sq
        //      (@13312); both zero-padded k in [100,104)
        for (int idx = t; idx < 64 * 13; idx += 512) {
            int row = idx / 13, cc = idx - row * 13;
            int kc = cc * 8;
            int il = row >> 3, col = row & 7;
            const float* sa_il  = sa  + il * 100;
            const float* sam_il = sam + il * 100;
            const float* sax_il = sax + il * 100;
            const float* p1 = (col >= 4) ? (col == 4 ? sl : col == 5 ? sam_il : sax_il)
                                         : sa_il;
            const float* p2 = (col == 0 || col == 4) ? sl :
                              (col == 1 || col == 5) ? sam_il :
                              (col == 2 || col == 6) ? sax_il : sa_il;
            u32 ow[4];
            #pragma unroll
            for (int e2 = 0; e2 < 4; ++e2) {
                int k0 = kc + 2 * e2;
                float f0 = (col < 7 && k0 < H)     ? p1[k0] * p2[k0]         : 0.f;
                float f1 = (col < 7 && k0 + 1 < H) ? p1[k0 + 1] * p2[k0 + 1] : 0.f;
                ow[e2] = pack2(f0, f1);
            }
            uint4 o = {ow[0], ow[1], ow[2], ow[3]};
            *(uint4*)(smem + row * 208 + kc * 2) = o;
        }
        for (int idx = t; idx < 64 * 13; idx += 512) {
            int kc = (idx % 13) * 8;
            int row = idx / 13;
            u32 ow[4];
            #pragma unroll
            for (int e2 = 0; e2 < 4; ++e2) {
                int k0 = kc + 2 * e2;
                float f0 = 0.f, f1 = 0.f;
                if (row < 60) {
                    const float* wr = (row < 20) ? w0 + row * H :
                                      (row < 40) ? w2 + (row - 20) * H :
                                                   w3 + (row - 40) * H;
                    if (k0 < H)     { float w = wr[k0];     f0 = w * w; }
                    if (k0 + 1 < H) { float w = wr[k0 + 1]; f1 = w * w; }
                } else if (row == 60) {
                    f0 = (k0 < H) ? 1.f : 0.f;
                    f1 = (k0 + 1 < H) ? 1.f : 0.f;
                }
                ow[e2] = pack2(f0, f1);
            }
            uint4 o = {ow[0], ow[1], ow[2], ow[3]};
            *(uint4*)(smem + 13312 + row * 208 + kc * 2) = o;
        }
        __syncthreads();

        // ---- phase 3b: D[61x7] = w2sq x Bcols^T per il (wave wv -> il=wv).
        //      ks==3,q>0 (k>=104): BOTH operands zeroed (OOB garbage).
        f4 d3[4];
        #pragma unroll
        for (int Mt = 0; Mt < 4; ++Mt) d3[Mt] = (f4){0.f, 0.f, 0.f, 0.f};
        {
            const int cn = m & 7;
            #pragma unroll
            for (int ks = 0; ks < 4; ++ks) {
                const int ko2 = (ks * 32 + q * 8) * 2;
                const bool oob = (ks == 3) && (q > 0);
                sh8 bb = oob ? zfrag()
                             : *(const sh8*)(smem + (wv * 8 + cn) * 208 + ko2);
                #pragma unroll
                for (int Mt = 0; Mt < 4; ++Mt) {
                    sh8 aa = oob ? zfrag()
                                 : *(const sh8*)(smem + 13312 + (Mt * 16 + m) * 208 + ko2);
                    d3[Mt] = __builtin_amdgcn_mfma_f32_16x16x32_bf16(aa, bb, d3[Mt], 0, 0, 0);
                }
            }
        }
        __syncthreads();   // all MFMA reads done before Dscr overwrites

        if (m < 8) {       // Dscr stride 9 dwords
            #pragma unroll
            for (int Mt = 0; Mt < 4; ++Mt)
                #pragma unroll
                for (int reg = 0; reg < 4; ++reg)
                    ((float*)smem)[wv * 576 + (Mt * 16 + q * 4 + reg) * 9 + m] = d3[Mt][reg];
        }
        __syncthreads();

        // ---- phase 3c: 504 output channels from Dscr
        for (int task = t; task < TI * 63; task += 512) {
            const int il = task / 63, c = task - il * 63;
            int row, dcol, nbcol, chn;
            if (c < 60) {
                const int grp = c / 20;
                row = c; dcol = grp; nbcol = 4 + grp;
                chn = ((grp == 0) ? 3 : (grp == 1) ? 64 : 85) + (c - grp * 20);
            } else {
                const int cc = c - 60;
                row = 60; dcol = cc; nbcol = 4 + cc;
                chn = (cc == 0) ? 2 : (cc == 1) ? 63 : 84;
            }
            const float* Dr = (const float*)smem + il * 576 + row * 9;
            float d = Dr[dcol], na = Dr[3], nb = Dr[nbcol];
            outBase[(size_t)(i0 + il) * C + chn] =
                d / (fmaxf(sqrtf(na), EPSF) * fmaxf(sqrtf(nb), EPSF));
        }
    }
}

// ---------------------------------------------------------------- launch
extern "C" void kernel_launch(void* const* d_in, const int* in_sizes, int n_in,
                              void* d_out, int out_size, void* d_ws, size_t ws_size,
                              hipStream_t stream)
{
    const float* ctx_p = (const float*)d_in[0];
    const int*   mask_p = (const int*)d_in[1];
    const float* ctx_h = (const float*)d_in[2];
    const int*   mask_h = (const int*)d_in[3];
    const float* w0 = (const float*)d_in[4];
    const float* w1 = (const float*)d_in[5];
    const float* w2 = (const float*)d_in[6];
    const float* w3 = (const float*)d_in[7];
    float* out = (float*)d_out;

    float* ws   = (float*)d_ws;
    float* cp   = ws;                       // B*L*H
    float* ch   = cp   + B * L * H;
    float* np_  = ch   + B * L * H;         // B*L
    float* nh_  = np_  + B * L;
    float* nw1p = nh_  + B * L;             // B*L*P
    float* nw1h = nw1p + B * L * P;
    u16*   cpb  = (u16*)(nw1h + B * L * P); // B*L*128 u16
    u16*   chb  = cpb + B * L * 128;

    k_prep<<<dim3(L / 8, B, 2), dim3(512), 0, stream>>>(
        ctx_p, mask_p, ctx_h, mask_h, w1,
        cp, ch, cpb, chb, np_, nh_, nw1p, nw1h);
    k_main<<<dim3(P + 32, B), dim3(512), 0, stream>>>(
        cp, ch, cpb, chb, np_, nh_, nw1p, nw1h, mask_p, mask_h,
        w0, w1, w2, w3, out);
}